// Round 1
// baseline (836.558 us; speedup 1.0000x reference)
//
#include <hip/hip_runtime.h>

// ---------------------------------------------------------------------------
// GCN forward: 4x (GEMM 50000x128x128 + pull-based CSR aggregation) + pool +
// linear + softmax. All fp32.
// ---------------------------------------------------------------------------

__device__ __forceinline__ int idx_at(const void* p, long long i, int is64) {
  return is64 ? (int)((const long long*)p)[i] : ((const int*)p)[i];
}

// Detect whether index arrays are int64 (odd int32 words all zero) or int32.
__global__ void k_detect(const int* __restrict__ edge, int* __restrict__ flag) {
  if (threadIdx.x == 0 && blockIdx.x == 0) {
    int all0 = 1;
    for (int i = 1; i < 128; i += 2)
      if (edge[i] != 0) { all0 = 0; break; }
    *flag = all0;
  }
}

__global__ void k_count(const void* __restrict__ edge, int E,
                        int* __restrict__ cnt, const int* __restrict__ flag) {
  int e = blockIdx.x * 256 + threadIdx.x;
  int is64 = *flag;
  if (e < E) {
    int c = idx_at(edge, (long long)E + e, is64);  // col = target
    atomicAdd(&cnt[c], 1);
  }
}

__global__ void k_dinv(const int* __restrict__ cnt, int n, float* __restrict__ dinv) {
  int i = blockIdx.x * 256 + threadIdx.x;
  if (i < n) dinv[i] = rsqrtf((float)(cnt[i] + 1));  // +1 self loop, always > 0
}

// --- 3-kernel exclusive scan over cnt[n] -> offs[n] (chunk 256) -------------
__global__ void k_scan1(const int* __restrict__ cnt, int* __restrict__ offs,
                        int* __restrict__ bsum, int n) {
  __shared__ int lds[256];
  int i = blockIdx.x * 256 + threadIdx.x;
  int v = (i < n) ? cnt[i] : 0;
  lds[threadIdx.x] = v;
  __syncthreads();
  for (int off = 1; off < 256; off <<= 1) {
    int t = (threadIdx.x >= off) ? lds[threadIdx.x - off] : 0;
    __syncthreads();
    lds[threadIdx.x] += t;
    __syncthreads();
  }
  if (i < n) offs[i] = lds[threadIdx.x] - v;  // exclusive within chunk
  if (threadIdx.x == 255) bsum[blockIdx.x] = lds[255];
}

__global__ void k_scan2(int* __restrict__ bsum, int nb) {
  __shared__ int lds[256];
  int v = (threadIdx.x < nb) ? bsum[threadIdx.x] : 0;
  lds[threadIdx.x] = v;
  __syncthreads();
  for (int off = 1; off < 256; off <<= 1) {
    int t = (threadIdx.x >= off) ? lds[threadIdx.x - off] : 0;
    __syncthreads();
    lds[threadIdx.x] += t;
    __syncthreads();
  }
  if (threadIdx.x < nb) bsum[threadIdx.x] = lds[threadIdx.x] - v;  // excl block prefix
}

__global__ void k_scan3(int* __restrict__ offs, int* __restrict__ cursor,
                        const int* __restrict__ bsum, int n, int E) {
  int i = blockIdx.x * 256 + threadIdx.x;
  if (i < n) {
    int o = offs[i] + bsum[blockIdx.x];
    offs[i] = o;
    cursor[i] = o;
  }
  if (i == 0) offs[n] = E;
}

__global__ void k_fill(const void* __restrict__ edge, int E,
                       const float* __restrict__ dinv, int* __restrict__ cursor,
                       int* __restrict__ csr_row, float* __restrict__ csr_norm,
                       const int* __restrict__ flag) {
  int e = blockIdx.x * 256 + threadIdx.x;
  int is64 = *flag;
  if (e < E) {
    int r = idx_at(edge, e, is64);
    int c = idx_at(edge, (long long)E + e, is64);
    int p = atomicAdd(&cursor[c], 1);
    csr_row[p] = r;
    csr_norm[p] = dinv[r] * dinv[c];
  }
}

// --- GEMM: C[n x 128] = A[n x 128] @ W[128 x 128] ---------------------------
// 64-row tiles, W (64KB) + A-tile (32KB) in LDS, each thread 8 rows x 4 cols.
__global__ __launch_bounds__(256) void k_gemm(const float* __restrict__ A,
                                              const float* __restrict__ W,
                                              float* __restrict__ C,
                                              int n, int ntiles) {
  __shared__ float4 Ws[128 * 32];  // 64 KB
  __shared__ float4 As[64 * 32];   // 32 KB
  const float4* W4 = (const float4*)W;
  const float4* A4 = (const float4*)A;
  float4* C4 = (float4*)C;
  int t = threadIdx.x;
#pragma unroll
  for (int j = 0; j < 16; j++) Ws[t + 256 * j] = W4[t + 256 * j];
  int tr = t >> 5;        // 0..7  (row group)
  int tc = t & 31;        // 0..31 (col group of 4)
  for (int tile = blockIdx.x; tile < ntiles; tile += gridDim.x) {
    __syncthreads();  // prev-iter readers done (also covers Ws load, iter 0)
    int base = tile * 64;
#pragma unroll
    for (int j = 0; j < 8; j++) {
      int f = t + 256 * j;   // float4 index in tile (0..2047)
      int r = f >> 5;
      int gr = base + r;
      As[f] = (gr < n) ? A4[(size_t)gr * 32 + (f & 31)] : float4{0, 0, 0, 0};
    }
    __syncthreads();
    float4 acc[8];
#pragma unroll
    for (int ii = 0; ii < 8; ii++) acc[ii] = float4{0, 0, 0, 0};
#pragma unroll 4
    for (int k4 = 0; k4 < 32; k4++) {
      float4 w0 = Ws[(4 * k4 + 0) * 32 + tc];
      float4 w1 = Ws[(4 * k4 + 1) * 32 + tc];
      float4 w2 = Ws[(4 * k4 + 2) * 32 + tc];
      float4 w3 = Ws[(4 * k4 + 3) * 32 + tc];
#pragma unroll
      for (int ii = 0; ii < 8; ii++) {
        float4 a = As[(tr * 8 + ii) * 32 + k4];
        acc[ii].x += a.x * w0.x + a.y * w1.x + a.z * w2.x + a.w * w3.x;
        acc[ii].y += a.x * w0.y + a.y * w1.y + a.z * w2.y + a.w * w3.y;
        acc[ii].z += a.x * w0.z + a.y * w1.z + a.z * w2.z + a.w * w3.z;
        acc[ii].w += a.x * w0.w + a.y * w1.w + a.z * w2.w + a.w * w3.w;
      }
    }
#pragma unroll
    for (int ii = 0; ii < 8; ii++) {
      int gr = base + tr * 8 + ii;
      if (gr < n) C4[(size_t)gr * 32 + tc] = acc[ii];
    }
  }
}

// --- Pull aggregation: one wave per node, 2 floats/lane = 128 feats ---------
__global__ __launch_bounds__(256) void k_agg(const float* __restrict__ h,
                                             const int* __restrict__ offs,
                                             const int* __restrict__ csr_row,
                                             const float* __restrict__ csr_norm,
                                             const float* __restrict__ dinv,
                                             const float* __restrict__ bias,
                                             float* __restrict__ out,
                                             int n, int relu) {
  int node = blockIdx.x * 4 + (threadIdx.x >> 6);
  if (node >= n) return;
  int lane = threadIdx.x & 63;
  const float2* h2 = (const float2*)h;
  int s = offs[node], e = offs[node + 1];
  float dn = dinv[node];
  float2 self = h2[(size_t)node * 64 + lane];
  float ax = self.x * dn * dn;
  float ay = self.y * dn * dn;
  for (int i = s; i < e; i++) {
    int r = csr_row[i];
    float nm = csr_norm[i];
    float2 v = h2[(size_t)r * 64 + lane];
    ax += v.x * nm;
    ay += v.y * nm;
  }
  float2 bb = ((const float2*)bias)[lane];
  ax += bb.x;
  ay += bb.y;
  if (relu) { ax = fmaxf(ax, 0.f); ay = fmaxf(ay, 0.f); }
  ((float2*)out)[(size_t)node * 64 + lane] = float2{ax, ay};
}

// --- Mean pool per graph (batch is sorted) ----------------------------------
__global__ void k_pool(const float* __restrict__ h, const void* __restrict__ batch,
                       int n, float* __restrict__ pooled, const int* __restrict__ flag) {
  __shared__ int s_lo, s_hi;
  int g = blockIdx.x;
  if (threadIdx.x == 0) {
    int is64 = *flag;
    int lo = 0, hi = n;
    while (lo < hi) { int m = (lo + hi) >> 1; if (idx_at(batch, m, is64) < g) lo = m + 1; else hi = m; }
    s_lo = lo;
    int lo2 = lo, hi2 = n;
    while (lo2 < hi2) { int m = (lo2 + hi2) >> 1; if (idx_at(batch, m, is64) < g + 1) lo2 = m + 1; else hi2 = m; }
    s_hi = lo2;
  }
  __syncthreads();
  int lo = s_lo, hi = s_hi;
  int f = threadIdx.x;  // 128 threads
  float sum = 0.f;
  for (int i = lo; i < hi; i++) sum += h[(size_t)i * 128 + f];
  float c = (float)((hi - lo) > 1 ? (hi - lo) : 1);
  pooled[g * 128 + f] = sum / c;
}

// --- logits + softmax -------------------------------------------------------
__global__ void k_final(const float* __restrict__ pooled, const float* __restrict__ Wlin,
                        const float* __restrict__ blin, float* __restrict__ out,
                        int ngraphs) {
  int t = threadIdx.x;
  int g = t >> 4, c = t & 15;
  __shared__ float lds[64 * 16];
  if (g < ngraphs) {
    float acc = blin[c];
    for (int k = 0; k < 128; k++) acc += pooled[g * 128 + k] * Wlin[k * 16 + c];
    lds[t] = acc;
  }
  __syncthreads();
  if (g < ngraphs) {
    float m = -1e30f;
    for (int j = 0; j < 16; j++) m = fmaxf(m, lds[(g << 4) + j]);
    float s = 0.f;
    for (int j = 0; j < 16; j++) s += expf(lds[(g << 4) + j] - m);
    out[t] = expf(lds[t] - m) / s;
  }
}

extern "C" void kernel_launch(void* const* d_in, const int* in_sizes, int n_in,
                              void* d_out, int out_size, void* d_ws, size_t ws_size,
                              hipStream_t stream) {
  const float* x = (const float*)d_in[0];
  const void* edge = d_in[1];
  const void* batch = d_in[2];
  const float* W[4] = {(const float*)d_in[3], (const float*)d_in[5],
                       (const float*)d_in[7], (const float*)d_in[9]};
  const float* b[4] = {(const float*)d_in[4], (const float*)d_in[6],
                       (const float*)d_in[8], (const float*)d_in[10]};
  const float* Wlin = (const float*)d_in[11];
  const float* blin = (const float*)d_in[12];
  float* out = (float*)d_out;

  int n = in_sizes[0] / 128;
  int E = in_sizes[1] / 2;
  int ngraphs = out_size / 16;

  char* ws = (char*)d_ws;
  size_t off = 0;
  auto alloc = [&](size_t bytes) -> void* {
    void* p = ws + off;
    off = (off + bytes + 255) & ~(size_t)255;
    return p;
  };
  int* flag = (int*)alloc(4);
  int* cnt = (int*)alloc((size_t)n * 4);
  int* offs = (int*)alloc((size_t)(n + 1) * 4);
  int* cursor = (int*)alloc((size_t)n * 4);
  float* dinv = (float*)alloc((size_t)n * 4);
  int* bsum = (int*)alloc(1024 * 4);
  int* csr_row = (int*)alloc((size_t)E * 4);
  float* csr_norm = (float*)alloc((size_t)E * 4);
  float* bufA = (float*)alloc((size_t)n * 128 * 4);
  float* bufB = (float*)alloc((size_t)n * 128 * 4);
  float* pooled = (float*)alloc((size_t)ngraphs * 128 * 4);

  hipMemsetAsync(cnt, 0, (size_t)n * 4, stream);
  k_detect<<<1, 64, 0, stream>>>((const int*)edge, flag);
  k_count<<<(E + 255) / 256, 256, 0, stream>>>(edge, E, cnt, flag);
  k_dinv<<<(n + 255) / 256, 256, 0, stream>>>(cnt, n, dinv);
  int nb = (n + 255) / 256;
  k_scan1<<<nb, 256, 0, stream>>>(cnt, offs, bsum, n);
  k_scan2<<<1, 256, 0, stream>>>(bsum, nb);
  k_scan3<<<nb, 256, 0, stream>>>(offs, cursor, bsum, n, E);
  k_fill<<<(E + 255) / 256, 256, 0, stream>>>(edge, E, dinv, cursor, csr_row, csr_norm, flag);

  int ntiles = (n + 63) / 64;
  const float* cur = x;
  for (int l = 0; l < 4; l++) {
    k_gemm<<<256, 256, 0, stream>>>(cur, W[l], bufA, n, ntiles);
    k_agg<<<(n + 3) / 4, 256, 0, stream>>>(bufA, offs, csr_row, csr_norm, dinv,
                                           b[l], bufB, n, (l < 3) ? 1 : 0);
    cur = bufB;
  }
  k_pool<<<ngraphs, 128, 0, stream>>>(bufB, batch, n, pooled, flag);
  k_final<<<1, ngraphs * 16, 0, stream>>>(pooled, Wlin, blin, out, ngraphs);
}

// Round 2
// 656.683 us; speedup vs baseline: 1.2739x; 1.2739x over previous
//
#include <hip/hip_runtime.h>

// ---------------------------------------------------------------------------
// GCN forward: 4x (GEMM 50000x128x128 + pull-based CSR aggregation) + pool +
// linear + softmax. All fp32.
// ---------------------------------------------------------------------------

__device__ __forceinline__ int idx_at(const void* p, long long i, int is64) {
  return is64 ? (int)((const long long*)p)[i] : ((const int*)p)[i];
}

// Detect whether index arrays are int64 (odd int32 words all zero) or int32.
__global__ void k_detect(const int* __restrict__ edge, int* __restrict__ flag) {
  if (threadIdx.x == 0 && blockIdx.x == 0) {
    int all0 = 1;
    for (int i = 1; i < 128; i += 2)
      if (edge[i] != 0) { all0 = 0; break; }
    *flag = all0;
  }
}

__global__ void k_count(const void* __restrict__ edge, int E,
                        int* __restrict__ cnt, const int* __restrict__ flag) {
  int e = blockIdx.x * 256 + threadIdx.x;
  int is64 = *flag;
  if (e < E) {
    int c = idx_at(edge, (long long)E + e, is64);  // col = target
    atomicAdd(&cnt[c], 1);
  }
}

__global__ void k_dinv(const int* __restrict__ cnt, int n, float* __restrict__ dinv) {
  int i = blockIdx.x * 256 + threadIdx.x;
  if (i < n) dinv[i] = rsqrtf((float)(cnt[i] + 1));  // +1 self loop, always > 0
}

// --- 3-kernel exclusive scan over cnt[n] -> offs[n] (chunk 256) -------------
__global__ void k_scan1(const int* __restrict__ cnt, int* __restrict__ offs,
                        int* __restrict__ bsum, int n) {
  __shared__ int lds[256];
  int i = blockIdx.x * 256 + threadIdx.x;
  int v = (i < n) ? cnt[i] : 0;
  lds[threadIdx.x] = v;
  __syncthreads();
  for (int off = 1; off < 256; off <<= 1) {
    int t = (threadIdx.x >= off) ? lds[threadIdx.x - off] : 0;
    __syncthreads();
    lds[threadIdx.x] += t;
    __syncthreads();
  }
  if (i < n) offs[i] = lds[threadIdx.x] - v;  // exclusive within chunk
  if (threadIdx.x == 255) bsum[blockIdx.x] = lds[255];
}

__global__ void k_scan2(int* __restrict__ bsum, int nb) {
  __shared__ int lds[256];
  int v = (threadIdx.x < nb) ? bsum[threadIdx.x] : 0;
  lds[threadIdx.x] = v;
  __syncthreads();
  for (int off = 1; off < 256; off <<= 1) {
    int t = (threadIdx.x >= off) ? lds[threadIdx.x - off] : 0;
    __syncthreads();
    lds[threadIdx.x] += t;
    __syncthreads();
  }
  if (threadIdx.x < nb) bsum[threadIdx.x] = lds[threadIdx.x] - v;  // excl block prefix
}

__global__ void k_scan3(int* __restrict__ offs, int* __restrict__ cursor,
                        const int* __restrict__ bsum, int n, int E) {
  int i = blockIdx.x * 256 + threadIdx.x;
  if (i < n) {
    int o = offs[i] + bsum[blockIdx.x];
    offs[i] = o;
    cursor[i] = o;
  }
  if (i == 0) offs[n] = E;
}

__global__ void k_fill(const void* __restrict__ edge, int E,
                       const float* __restrict__ dinv, int* __restrict__ cursor,
                       int* __restrict__ csr_row, float* __restrict__ csr_norm,
                       const int* __restrict__ flag) {
  int e = blockIdx.x * 256 + threadIdx.x;
  int is64 = *flag;
  if (e < E) {
    int r = idx_at(edge, e, is64);
    int c = idx_at(edge, (long long)E + e, is64);
    int p = atomicAdd(&cursor[c], 1);
    csr_row[p] = r;
    csr_norm[p] = dinv[r] * dinv[c];
  }
}

// --- GEMM: C[n x 128] = A[n x 128] @ W[128 x 128] ---------------------------
// 64-row tiles, W (64KB) + A-tile (32KB) in LDS, each thread 8 rows x 4 cols.
__global__ __launch_bounds__(256) void k_gemm(const float* __restrict__ A,
                                              const float* __restrict__ W,
                                              float* __restrict__ C,
                                              int n, int ntiles) {
  __shared__ float4 Ws[128 * 32];  // 64 KB
  __shared__ float4 As[64 * 32];   // 32 KB
  const float4* W4 = (const float4*)W;
  const float4* A4 = (const float4*)A;
  float4* C4 = (float4*)C;
  int t = threadIdx.x;
#pragma unroll
  for (int j = 0; j < 16; j++) Ws[t + 256 * j] = W4[t + 256 * j];
  int tr = t >> 5;        // 0..7  (row group)
  int tc = t & 31;        // 0..31 (col group of 4)
  for (int tile = blockIdx.x; tile < ntiles; tile += gridDim.x) {
    __syncthreads();  // prev-iter readers done (also covers Ws load, iter 0)
    int base = tile * 64;
#pragma unroll
    for (int j = 0; j < 8; j++) {
      int f = t + 256 * j;   // float4 index in tile (0..2047)
      int r = f >> 5;
      int gr = base + r;
      As[f] = (gr < n) ? A4[(size_t)gr * 32 + (f & 31)] : float4{0, 0, 0, 0};
    }
    __syncthreads();
    float4 acc[8];
#pragma unroll
    for (int ii = 0; ii < 8; ii++) acc[ii] = float4{0, 0, 0, 0};
#pragma unroll 4
    for (int k4 = 0; k4 < 32; k4++) {
      float4 w0 = Ws[(4 * k4 + 0) * 32 + tc];
      float4 w1 = Ws[(4 * k4 + 1) * 32 + tc];
      float4 w2 = Ws[(4 * k4 + 2) * 32 + tc];
      float4 w3 = Ws[(4 * k4 + 3) * 32 + tc];
#pragma unroll
      for (int ii = 0; ii < 8; ii++) {
        float4 a = As[(tr * 8 + ii) * 32 + k4];
        acc[ii].x += a.x * w0.x + a.y * w1.x + a.z * w2.x + a.w * w3.x;
        acc[ii].y += a.x * w0.y + a.y * w1.y + a.z * w2.y + a.w * w3.y;
        acc[ii].z += a.x * w0.z + a.y * w1.z + a.z * w2.z + a.w * w3.z;
        acc[ii].w += a.x * w0.w + a.y * w1.w + a.z * w2.w + a.w * w3.w;
      }
    }
#pragma unroll
    for (int ii = 0; ii < 8; ii++) {
      int gr = base + tr * 8 + ii;
      if (gr < n) C4[(size_t)gr * 32 + tc] = acc[ii];
    }
  }
}

// --- Pull aggregation: one wave per node, 2 floats/lane = 128 feats ---------
__global__ __launch_bounds__(256) void k_agg(const float* __restrict__ h,
                                             const int* __restrict__ offs,
                                             const int* __restrict__ csr_row,
                                             const float* __restrict__ csr_norm,
                                             const float* __restrict__ dinv,
                                             const float* __restrict__ bias,
                                             float* __restrict__ out,
                                             int n, int relu) {
  int node = blockIdx.x * 4 + (threadIdx.x >> 6);
  if (node >= n) return;
  int lane = threadIdx.x & 63;
  const float2* h2 = (const float2*)h;
  int s = offs[node], e = offs[node + 1];
  float dn = dinv[node];
  float2 self = h2[(size_t)node * 64 + lane];
  float ax = self.x * dn * dn;
  float ay = self.y * dn * dn;
  for (int i = s; i < e; i++) {
    int r = csr_row[i];
    float nm = csr_norm[i];
    float2 v = h2[(size_t)r * 64 + lane];
    ax += v.x * nm;
    ay += v.y * nm;
  }
  float2 bb = ((const float2*)bias)[lane];
  ax += bb.x;
  ay += bb.y;
  if (relu) { ax = fmaxf(ax, 0.f); ay = fmaxf(ay, 0.f); }
  ((float2*)out)[(size_t)node * 64 + lane] = float2{ax, ay};
}

// --- Mean pool: chunked partial sums + atomics (batch sorted) ---------------
#define POOL_CH 64
__global__ __launch_bounds__(128) void k_pool_partial(
    const float* __restrict__ h, const void* __restrict__ batch, int n,
    float* __restrict__ sums, float* __restrict__ cnts,
    const int* __restrict__ flag) {
  int start = blockIdx.x * POOL_CH;
  if (start >= n) return;
  int end = start + POOL_CH;
  if (end > n) end = n;
  int f = threadIdx.x;  // 128 feature lanes
  int is64 = *flag;
  int g = idx_at(batch, start, is64);
  float acc = 0.f, c = 0.f;
  for (int i = start; i < end; i++) {
    int gi = idx_at(batch, i, is64);
    if (gi != g) {
      atomicAdd(&sums[g * 128 + f], acc);
      if (f == 0) atomicAdd(&cnts[g], c);
      acc = 0.f; c = 0.f; g = gi;
    }
    acc += h[(size_t)i * 128 + f];
    c += 1.f;
  }
  atomicAdd(&sums[g * 128 + f], acc);
  if (f == 0) atomicAdd(&cnts[g], c);
}

// --- logits + softmax (divides by counts) -----------------------------------
__global__ void k_final(const float* __restrict__ sums, const float* __restrict__ cnts,
                        const float* __restrict__ Wlin, const float* __restrict__ blin,
                        float* __restrict__ out, int ngraphs) {
  int t = threadIdx.x;
  int g = t >> 4, c = t & 15;
  __shared__ float lds[64 * 16];
  if (g < ngraphs) {
    float inv = 1.f / fmaxf(cnts[g], 1.f);
    float acc = 0.f;
    for (int k = 0; k < 128; k++) acc += sums[g * 128 + k] * Wlin[k * 16 + c];
    lds[t] = acc * inv + blin[c];
  }
  __syncthreads();
  if (g < ngraphs) {
    float m = -1e30f;
    for (int j = 0; j < 16; j++) m = fmaxf(m, lds[(g << 4) + j]);
    float s = 0.f;
    for (int j = 0; j < 16; j++) s += expf(lds[(g << 4) + j] - m);
    out[t] = expf(lds[t] - m) / s;
  }
}

extern "C" void kernel_launch(void* const* d_in, const int* in_sizes, int n_in,
                              void* d_out, int out_size, void* d_ws, size_t ws_size,
                              hipStream_t stream) {
  const float* x = (const float*)d_in[0];
  const void* edge = d_in[1];
  const void* batch = d_in[2];
  const float* W[4] = {(const float*)d_in[3], (const float*)d_in[5],
                       (const float*)d_in[7], (const float*)d_in[9]};
  const float* b[4] = {(const float*)d_in[4], (const float*)d_in[6],
                       (const float*)d_in[8], (const float*)d_in[10]};
  const float* Wlin = (const float*)d_in[11];
  const float* blin = (const float*)d_in[12];
  float* out = (float*)d_out;

  int n = in_sizes[0] / 128;
  int E = in_sizes[1] / 2;
  int ngraphs = out_size / 16;

  char* ws = (char*)d_ws;
  size_t off = 0;
  auto alloc = [&](size_t bytes) -> void* {
    void* p = ws + off;
    off = (off + bytes + 255) & ~(size_t)255;
    return p;
  };
  int* flag = (int*)alloc(4);
  int* cnt = (int*)alloc((size_t)n * 4);
  int* offs = (int*)alloc((size_t)(n + 1) * 4);
  int* cursor = (int*)alloc((size_t)n * 4);
  float* dinv = (float*)alloc((size_t)n * 4);
  int* bsum = (int*)alloc(1024 * 4);
  int* csr_row = (int*)alloc((size_t)E * 4);
  float* csr_norm = (float*)alloc((size_t)E * 4);
  float* bufA = (float*)alloc((size_t)n * 128 * 4);
  float* bufB = (float*)alloc((size_t)n * 128 * 4);
  float* sums = (float*)alloc((size_t)ngraphs * 128 * 4);
  float* cnts = (float*)alloc((size_t)ngraphs * 4);

  hipMemsetAsync(cnt, 0, (size_t)n * 4, stream);
  hipMemsetAsync(sums, 0, (size_t)ngraphs * 128 * 4, stream);
  hipMemsetAsync(cnts, 0, (size_t)ngraphs * 4, stream);
  k_detect<<<1, 64, 0, stream>>>((const int*)edge, flag);
  k_count<<<(E + 255) / 256, 256, 0, stream>>>(edge, E, cnt, flag);
  k_dinv<<<(n + 255) / 256, 256, 0, stream>>>(cnt, n, dinv);
  int nb = (n + 255) / 256;
  k_scan1<<<nb, 256, 0, stream>>>(cnt, offs, bsum, n);
  k_scan2<<<1, 256, 0, stream>>>(bsum, nb);
  k_scan3<<<nb, 256, 0, stream>>>(offs, cursor, bsum, n, E);
  k_fill<<<(E + 255) / 256, 256, 0, stream>>>(edge, E, dinv, cursor, csr_row, csr_norm, flag);

  int ntiles = (n + 63) / 64;
  const float* cur = x;
  for (int l = 0; l < 4; l++) {
    k_gemm<<<256, 256, 0, stream>>>(cur, W[l], bufA, n, ntiles);
    k_agg<<<(n + 3) / 4, 256, 0, stream>>>(bufA, offs, csr_row, csr_norm, dinv,
                                           b[l], bufB, n, (l < 3) ? 1 : 0);
    cur = bufB;
  }
  k_pool_partial<<<(n + POOL_CH - 1) / POOL_CH, 128, 0, stream>>>(bufB, batch, n, sums, cnts, flag);
  k_final<<<1, ngraphs * 16, 0, stream>>>(sums, cnts, Wlin, blin, out, ngraphs);
}

// Round 3
// 482.483 us; speedup vs baseline: 1.7339x; 1.3610x over previous
//
#include <hip/hip_runtime.h>

// ---------------------------------------------------------------------------
// GCN forward: 4x (GEMM 50000x128x128 + pull-based CSR aggregation) + pool +
// linear + softmax. All fp32.
// ---------------------------------------------------------------------------

__device__ __forceinline__ int idx_at(const void* p, long long i, int is64) {
  return is64 ? (int)((const long long*)p)[i] : ((const int*)p)[i];
}

// Detect whether index arrays are int64 (odd int32 words all zero) or int32.
__global__ void k_detect(const int* __restrict__ edge, int* __restrict__ flag) {
  if (threadIdx.x == 0 && blockIdx.x == 0) {
    int all0 = 1;
    for (int i = 1; i < 128; i += 2)
      if (edge[i] != 0) { all0 = 0; break; }
    *flag = all0;
  }
}

__global__ void k_count(const void* __restrict__ edge, int E,
                        int* __restrict__ cnt, const int* __restrict__ flag) {
  int e = blockIdx.x * 256 + threadIdx.x;
  int is64 = *flag;
  if (e < E) {
    int c = idx_at(edge, (long long)E + e, is64);  // col = target
    atomicAdd(&cnt[c], 1);
  }
}

__global__ void k_dinv(const int* __restrict__ cnt, int n, float* __restrict__ dinv) {
  int i = blockIdx.x * 256 + threadIdx.x;
  if (i < n) dinv[i] = rsqrtf((float)(cnt[i] + 1));  // +1 self loop, always > 0
}

// --- 3-kernel exclusive scan over cnt[n] -> offs[n] (chunk 256) -------------
__global__ void k_scan1(const int* __restrict__ cnt, int* __restrict__ offs,
                        int* __restrict__ bsum, int n) {
  __shared__ int lds[256];
  int i = blockIdx.x * 256 + threadIdx.x;
  int v = (i < n) ? cnt[i] : 0;
  lds[threadIdx.x] = v;
  __syncthreads();
  for (int off = 1; off < 256; off <<= 1) {
    int t = (threadIdx.x >= off) ? lds[threadIdx.x - off] : 0;
    __syncthreads();
    lds[threadIdx.x] += t;
    __syncthreads();
  }
  if (i < n) offs[i] = lds[threadIdx.x] - v;  // exclusive within chunk
  if (threadIdx.x == 255) bsum[blockIdx.x] = lds[255];
}

__global__ void k_scan2(int* __restrict__ bsum, int nb) {
  __shared__ int lds[256];
  int v = (threadIdx.x < nb) ? bsum[threadIdx.x] : 0;
  lds[threadIdx.x] = v;
  __syncthreads();
  for (int off = 1; off < 256; off <<= 1) {
    int t = (threadIdx.x >= off) ? lds[threadIdx.x - off] : 0;
    __syncthreads();
    lds[threadIdx.x] += t;
    __syncthreads();
  }
  if (threadIdx.x < nb) bsum[threadIdx.x] = lds[threadIdx.x] - v;  // excl block prefix
}

__global__ void k_scan3(int* __restrict__ offs, int* __restrict__ cursor,
                        const int* __restrict__ bsum, int n, int E) {
  int i = blockIdx.x * 256 + threadIdx.x;
  if (i < n) {
    int o = offs[i] + bsum[blockIdx.x];
    offs[i] = o;
    cursor[i] = o;
  }
  if (i == 0) offs[n] = E;
}

// csr_pair[p] = {source_row, bitcast(norm)}
__global__ void k_fill(const void* __restrict__ edge, int E,
                       const float* __restrict__ dinv, int* __restrict__ cursor,
                       int2* __restrict__ csr_pair, const int* __restrict__ flag) {
  int e = blockIdx.x * 256 + threadIdx.x;
  int is64 = *flag;
  if (e < E) {
    int r = idx_at(edge, e, is64);
    int c = idx_at(edge, (long long)E + e, is64);
    int p = atomicAdd(&cursor[c], 1);
    float nm = dinv[r] * dinv[c];
    csr_pair[p] = int2{r, __float_as_int(nm)};
  }
}

// --- GEMM: C[n x 128] = A[n x 128] @ W[128 x 128] ---------------------------
// A-tile only in LDS (padded stride 33 to kill bank conflicts); W read from
// global (L1/L2-hot, coalesced+broadcast). 33.8 KB LDS -> 4 blocks/CU.
#define GR 64
__global__ __launch_bounds__(256) void k_gemm(const float* __restrict__ A,
                                              const float* __restrict__ W,
                                              float* __restrict__ C,
                                              int n, int ntiles) {
  __shared__ float4 As[GR * 33];  // 33.8 KB, stride 33 float4s
  const float4* W4 = (const float4*)W;
  const float4* A4 = (const float4*)A;
  float4* C4 = (float4*)C;
  int t = threadIdx.x;
  int tr = t >> 5;   // 0..7 (row group of 8)
  int tc = t & 31;   // 0..31 (col group of 4)
  for (int tile = blockIdx.x; tile < ntiles; tile += gridDim.x) {
    __syncthreads();
    int base = tile * GR;
#pragma unroll
    for (int j = 0; j < 8; j++) {
      int f = t + 256 * j;           // 0..2047
      int r = f >> 5, ccol = f & 31;
      int gr = base + r;
      As[r * 33 + ccol] = (gr < n) ? A4[(size_t)gr * 32 + ccol] : float4{0, 0, 0, 0};
    }
    __syncthreads();
    float4 acc[8];
#pragma unroll
    for (int ii = 0; ii < 8; ii++) acc[ii] = float4{0, 0, 0, 0};
#pragma unroll 4
    for (int k4 = 0; k4 < 32; k4++) {
      float4 w0 = W4[(4 * k4 + 0) * 32 + tc];
      float4 w1 = W4[(4 * k4 + 1) * 32 + tc];
      float4 w2 = W4[(4 * k4 + 2) * 32 + tc];
      float4 w3 = W4[(4 * k4 + 3) * 32 + tc];
#pragma unroll
      for (int ii = 0; ii < 8; ii++) {
        float4 a = As[(tr * 8 + ii) * 33 + k4];
        acc[ii].x += a.x * w0.x + a.y * w1.x + a.z * w2.x + a.w * w3.x;
        acc[ii].y += a.x * w0.y + a.y * w1.y + a.z * w2.y + a.w * w3.y;
        acc[ii].z += a.x * w0.z + a.y * w1.z + a.z * w2.z + a.w * w3.z;
        acc[ii].w += a.x * w0.w + a.y * w1.w + a.z * w2.w + a.w * w3.w;
      }
    }
#pragma unroll
    for (int ii = 0; ii < 8; ii++) {
      int gr = base + tr * 8 + ii;
      if (gr < n) C4[(size_t)gr * 32 + tc] = acc[ii];
    }
  }
}

// --- Pull aggregation: one wave per node, 2 floats/lane, 4-deep pipeline ----
__global__ __launch_bounds__(256) void k_agg(const float* __restrict__ h,
                                             const int* __restrict__ offs,
                                             const int2* __restrict__ csr_pair,
                                             const float* __restrict__ dinv,
                                             const float* __restrict__ bias,
                                             float* __restrict__ out,
                                             int n, int relu) {
  int node = blockIdx.x * 4 + (threadIdx.x >> 6);
  if (node >= n) return;
  int lane = threadIdx.x & 63;
  const float2* h2 = (const float2*)h;
  int s = offs[node], e = offs[node + 1];
  float dn = dinv[node];
  float2 self = h2[(size_t)node * 64 + lane];
  float ax = self.x * dn * dn;
  float ay = self.y * dn * dn;
  int i = s;
  for (; i + 4 <= e; i += 4) {
    int2 p0 = csr_pair[i];
    int2 p1 = csr_pair[i + 1];
    int2 p2 = csr_pair[i + 2];
    int2 p3 = csr_pair[i + 3];
    float2 v0 = h2[(size_t)p0.x * 64 + lane];
    float2 v1 = h2[(size_t)p1.x * 64 + lane];
    float2 v2 = h2[(size_t)p2.x * 64 + lane];
    float2 v3 = h2[(size_t)p3.x * 64 + lane];
    float f0 = __int_as_float(p0.y), f1 = __int_as_float(p1.y);
    float f2 = __int_as_float(p2.y), f3 = __int_as_float(p3.y);
    ax += v0.x * f0; ay += v0.y * f0;
    ax += v1.x * f1; ay += v1.y * f1;
    ax += v2.x * f2; ay += v2.y * f2;
    ax += v3.x * f3; ay += v3.y * f3;
  }
  for (; i < e; i++) {
    int2 p = csr_pair[i];
    float2 v = h2[(size_t)p.x * 64 + lane];
    float f = __int_as_float(p.y);
    ax += v.x * f;
    ay += v.y * f;
  }
  float2 bb = ((const float2*)bias)[lane];
  ax += bb.x;
  ay += bb.y;
  if (relu) { ax = fmaxf(ax, 0.f); ay = fmaxf(ay, 0.f); }
  ((float2*)out)[(size_t)node * 64 + lane] = float2{ax, ay};
}

// --- Mean pool: chunked partial sums + atomics (batch sorted) ---------------
#define POOL_CH 64
__global__ __launch_bounds__(128) void k_pool_partial(
    const float* __restrict__ h, const void* __restrict__ batch, int n,
    float* __restrict__ sums, float* __restrict__ cnts,
    const int* __restrict__ flag) {
  int start = blockIdx.x * POOL_CH;
  if (start >= n) return;
  int end = start + POOL_CH;
  if (end > n) end = n;
  int f = threadIdx.x;  // 128 feature lanes
  int is64 = *flag;
  int g = idx_at(batch, start, is64);
  float acc = 0.f, c = 0.f;
  for (int i = start; i < end; i++) {
    int gi = idx_at(batch, i, is64);
    if (gi != g) {
      atomicAdd(&sums[g * 128 + f], acc);
      if (f == 0) atomicAdd(&cnts[g], c);
      acc = 0.f; c = 0.f; g = gi;
    }
    acc += h[(size_t)i * 128 + f];
    c += 1.f;
  }
  atomicAdd(&sums[g * 128 + f], acc);
  if (f == 0) atomicAdd(&cnts[g], c);
}

// --- logits + softmax (divides by counts) -----------------------------------
__global__ void k_final(const float* __restrict__ sums, const float* __restrict__ cnts,
                        const float* __restrict__ Wlin, const float* __restrict__ blin,
                        float* __restrict__ out, int ngraphs) {
  int t = threadIdx.x;
  int g = t >> 4, c = t & 15;
  __shared__ float lds[64 * 16];
  if (g < ngraphs) {
    float inv = 1.f / fmaxf(cnts[g], 1.f);
    float acc = 0.f;
    for (int k = 0; k < 128; k++) acc += sums[g * 128 + k] * Wlin[k * 16 + c];
    lds[t] = acc * inv + blin[c];
  }
  __syncthreads();
  if (g < ngraphs) {
    float m = -1e30f;
    for (int j = 0; j < 16; j++) m = fmaxf(m, lds[(g << 4) + j]);
    float s = 0.f;
    for (int j = 0; j < 16; j++) s += expf(lds[(g << 4) + j] - m);
    out[t] = expf(lds[t] - m) / s;
  }
}

extern "C" void kernel_launch(void* const* d_in, const int* in_sizes, int n_in,
                              void* d_out, int out_size, void* d_ws, size_t ws_size,
                              hipStream_t stream) {
  const float* x = (const float*)d_in[0];
  const void* edge = d_in[1];
  const void* batch = d_in[2];
  const float* W[4] = {(const float*)d_in[3], (const float*)d_in[5],
                       (const float*)d_in[7], (const float*)d_in[9]};
  const float* b[4] = {(const float*)d_in[4], (const float*)d_in[6],
                       (const float*)d_in[8], (const float*)d_in[10]};
  const float* Wlin = (const float*)d_in[11];
  const float* blin = (const float*)d_in[12];
  float* out = (float*)d_out;

  int n = in_sizes[0] / 128;
  int E = in_sizes[1] / 2;
  int ngraphs = out_size / 16;

  char* ws = (char*)d_ws;
  size_t off = 0;
  auto alloc = [&](size_t bytes) -> void* {
    void* p = ws + off;
    off = (off + bytes + 255) & ~(size_t)255;
    return p;
  };
  int* flag = (int*)alloc(4);
  int* cnt = (int*)alloc((size_t)n * 4);
  int* offs = (int*)alloc((size_t)(n + 1) * 4);
  int* cursor = (int*)alloc((size_t)n * 4);
  float* dinv = (float*)alloc((size_t)n * 4);
  int* bsum = (int*)alloc(1024 * 4);
  int2* csr_pair = (int2*)alloc((size_t)E * 8);
  float* bufA = (float*)alloc((size_t)n * 128 * 4);
  float* bufB = (float*)alloc((size_t)n * 128 * 4);
  float* sums = (float*)alloc((size_t)ngraphs * 128 * 4);
  float* cnts = (float*)alloc((size_t)ngraphs * 4);

  hipMemsetAsync(cnt, 0, (size_t)n * 4, stream);
  hipMemsetAsync(sums, 0, (size_t)ngraphs * 128 * 4, stream);
  hipMemsetAsync(cnts, 0, (size_t)ngraphs * 4, stream);
  k_detect<<<1, 64, 0, stream>>>((const int*)edge, flag);
  k_count<<<(E + 255) / 256, 256, 0, stream>>>(edge, E, cnt, flag);
  k_dinv<<<(n + 255) / 256, 256, 0, stream>>>(cnt, n, dinv);
  int nb = (n + 255) / 256;
  k_scan1<<<nb, 256, 0, stream>>>(cnt, offs, bsum, n);
  k_scan2<<<1, 256, 0, stream>>>(bsum, nb);
  k_scan3<<<nb, 256, 0, stream>>>(offs, cursor, bsum, n, E);
  k_fill<<<(E + 255) / 256, 256, 0, stream>>>(edge, E, dinv, cursor, csr_pair, flag);

  int ntiles = (n + GR - 1) / GR;
  const float* cur = x;
  for (int l = 0; l < 4; l++) {
    k_gemm<<<ntiles, 256, 0, stream>>>(cur, W[l], bufA, n, ntiles);
    k_agg<<<(n + 3) / 4, 256, 0, stream>>>(bufA, offs, csr_pair, dinv,
                                           b[l], bufB, n, (l < 3) ? 1 : 0);
    cur = bufB;
  }
  k_pool_partial<<<(n + POOL_CH - 1) / POOL_CH, 128, 0, stream>>>(bufB, batch, n, sums, cnts, flag);
  k_final<<<1, ngraphs * 16, 0, stream>>>(sums, cnts, Wlin, blin, out, ngraphs);
}